// Round 5
// baseline (243.658 us; speedup 1.0000x reference)
//
#include <hip/hip_runtime.h>
#include <hip/hip_bf16.h>
#include <cstddef>

#define N 8192
#define D 256
#define BI 128
#define KT 32
#define PK 40              // LDS row stride in ushort (32 + 8 pad = 80 B = 20 words; 20 coprime-ish with 32 banks)
#define NT (N / BI)        // 64 row tiles

typedef __attribute__((ext_vector_type(8))) short short8;   // 8 bf16 = one MFMA A/B frag
typedef __attribute__((ext_vector_type(4))) float float4v;  // MFMA C/D frag

__device__ inline ushort f2bf(float x) {
    __hip_bfloat16 h = __float2bfloat16(x);
    return __builtin_bit_cast(ushort, h);
}
__device__ inline float bf2f(ushort u) {
    __hip_bfloat16 h = __builtin_bit_cast(__hip_bfloat16, u);
    return __bfloat162float(h);
}

// sortable pack: (monotone-uint(key) << 32) | idx  -> atomicMin == argmin with lowest-idx tie-break
__device__ inline unsigned long long packKI(float k, int idx) {
    unsigned u = __float_as_uint(k);
    u = (u & 0x80000000u) ? ~u : (u | 0x80000000u);
    return ((unsigned long long)u << 32) | (unsigned)idx;
}

// ---------------- K0: init packed-argmin array ----------------
__global__ void init_kernel(unsigned long long* __restrict__ M) {
    int i = blockIdx.x * blockDim.x + threadIdx.x;
    if (i < N) M[i] = 0xFFFFFFFFFFFFFFFFull;
}

// ---------------- K1: copy e_actv and e_ap into out[0 : 2*N*D) ----------------
__global__ void copy_kernel(const float4* __restrict__ a, const float4* __restrict__ p,
                            float4* __restrict__ out) {
    int idx = blockIdx.x * blockDim.x + threadIdx.x;
    const int total = N * D / 4;
    if (idx < total) out[idx] = a[idx];
    else             out[idx] = p[idx - total];
}

// ---------------- K2: squared row norms (fp32 exact) ----------------
__global__ void sqnorm_kernel(const float* __restrict__ e, float* __restrict__ sq) {
    int row = blockIdx.x;
    int t = threadIdx.x;   // 64
    const float4* r4 = (const float4*)(e + (size_t)row * D);
    float4 v = r4[t];
    float s = v.x * v.x + v.y * v.y + v.z * v.z + v.w * v.w;
    #pragma unroll
    for (int off = 32; off; off >>= 1) s += __shfl_down(s, off);
    if (t == 0) sq[row] = s;
}

// ---------------- K3: split fp32 -> bf16 hi + bf16 lo ----------------
__global__ void split_kernel(const float4* __restrict__ E,
                             ushort4* __restrict__ hi, ushort4* __restrict__ lo) {
    int idx = blockIdx.x * blockDim.x + threadIdx.x;   // over N*D/4
    float4 v = E[idx];
    ushort4 h, l;
    h.x = f2bf(v.x); l.x = f2bf(v.x - bf2f(h.x));
    h.y = f2bf(v.y); l.y = f2bf(v.y - bf2f(h.y));
    h.z = f2bf(v.z); l.z = f2bf(v.z - bf2f(h.z));
    h.w = f2bf(v.w); l.w = f2bf(v.w - bf2f(h.w));
    hi[idx] = h; lo[idx] = l;
}

// ---------------- K4: symmetric split-bf16 MFMA + dual-sided masked argmin ----------------
// Upper-triangle tiles only (ti <= tj): each 128x128 tile of dot(i,j) updates
//   rows side: argmin_i over j with key = sq[j] - 2*dot
//   cols side: argmin_j over i with key = sq[i] - 2*dot   (skipped on diagonal)
// Partials merged globally via atomicMin on packed (key,idx).
__launch_bounds__(256)
__global__ void argmin_sym(const ushort* __restrict__ Ehi, const ushort* __restrict__ Elo,
                           const int* __restrict__ host, const float* __restrict__ sq,
                           unsigned long long* __restrict__ M) {
    const int ti = blockIdx.y;
    const int tj = blockIdx.x;
    if (tj < ti) return;                        // lower triangle: exit immediately

    __shared__ __align__(16) ushort lds[4 * BI * PK];   // 40960 B
    __shared__ float sqA_s[BI], sqB_s[BI];
    __shared__ int   hostB_s[BI];
    ushort* Ahi_s = lds;
    ushort* Alo_s = lds + 1 * BI * PK;
    ushort* Bhi_s = lds + 2 * BI * PK;
    ushort* Blo_s = lds + 3 * BI * PK;

    const int ib0 = ti * BI;
    const int jb0 = tj * BI;
    const int tid = threadIdx.x;
    const int lane = tid & 63;
    const int wave = tid >> 6;      // 0..3
    const int wrow = wave >> 1;     // 0..1
    const int wcol = wave & 1;      // 0..1
    const int tx = lane & 15;       // 0..15
    const int q  = lane >> 4;       // 0..3

    // hostA packed per rt: 4 bytes = hosts of rows (rt,reg) for this lane (host < 64)
    unsigned hostAp[4];
    #pragma unroll
    for (int rt = 0; rt < 4; rt++) {
        unsigned p = 0;
        #pragma unroll
        for (int reg = 0; reg < 4; reg++) {
            int hv = host[ib0 + wrow * 64 + rt * 16 + q * 4 + reg];
            p |= ((unsigned)hv & 0xFFu) << (8 * reg);
        }
        hostAp[rt] = p;
    }

    float4v acc[4][4];   // [rt][ct]
    #pragma unroll
    for (int rt = 0; rt < 4; rt++)
        #pragma unroll
        for (int ct = 0; ct < 4; ct++) acc[rt][ct] = (float4v)(0.0f);

    for (int kt = 0; kt < D; kt += KT) {
        __syncthreads();
        // stage 4 arrays: 128 rows x 32 bf16; 512 16B-chunks per array; 2 per thread per array
        #pragma unroll
        for (int t = 0; t < 2; t++) {
            int f = tid + t * 256;       // 0..511
            int row = f >> 2;            // 0..127
            int c = f & 3;               // 16B chunk within 64B row slice
            size_t gA = (size_t)(ib0 + row) * D + kt + c * 8;
            size_t gB = (size_t)(jb0 + row) * D + kt + c * 8;
            int o = row * PK + c * 8;
            *(uint4*)&Ahi_s[o] = *(const uint4*)&Ehi[gA];
            *(uint4*)&Alo_s[o] = *(const uint4*)&Elo[gA];
            *(uint4*)&Bhi_s[o] = *(const uint4*)&Ehi[gB];
            *(uint4*)&Blo_s[o] = *(const uint4*)&Elo[gB];
        }
        if (kt == 0 && tid < BI) {
            sqA_s[tid] = sq[ib0 + tid];
            sqB_s[tid] = sq[jb0 + tid];
            hostB_s[tid] = host[jb0 + tid];
        }
        __syncthreads();

        short8 ah[4], al[4], bh[4], bl[4];
        #pragma unroll
        for (int rt = 0; rt < 4; rt++) {
            int o = (wrow * 64 + rt * 16 + tx) * PK + q * 8;
            ah[rt] = *(const short8*)&Ahi_s[o];
            al[rt] = *(const short8*)&Alo_s[o];
        }
        #pragma unroll
        for (int ct = 0; ct < 4; ct++) {
            int o = (wcol * 64 + ct * 16 + tx) * PK + q * 8;
            bh[ct] = *(const short8*)&Bhi_s[o];
            bl[ct] = *(const short8*)&Blo_s[o];
        }
        #pragma unroll
        for (int rt = 0; rt < 4; rt++)
            #pragma unroll
            for (int ct = 0; ct < 4; ct++) {
                acc[rt][ct] = __builtin_amdgcn_mfma_f32_16x16x32_bf16(ah[rt], bh[ct], acc[rt][ct], 0, 0, 0);
                acc[rt][ct] = __builtin_amdgcn_mfma_f32_16x16x32_bf16(ah[rt], bl[ct], acc[rt][ct], 0, 0, 0);
                acc[rt][ct] = __builtin_amdgcn_mfma_f32_16x16x32_bf16(al[rt], bh[ct], acc[rt][ct], 0, 0, 0);
            }
    }

    // ---- epilogue: dual-sided argmin. Reuse lds head as reduction scratch. ----
    __syncthreads();                       // all frag reads done before scratch overwrite
    float* rowV = (float*)lds;             // [128][2] (by wcol)
    int*   rowI = (int*)lds + 256;
    float* colV = (float*)lds + 512;       // [128][2] (by wrow)
    int*   colI = (int*)lds + 768;

    // rows side: for each of this lane's 16 rows, min over its 4 ct entries, then over tx
    #pragma unroll
    for (int rt = 0; rt < 4; rt++) {
        unsigned hp = hostAp[rt];
        #pragma unroll
        for (int reg = 0; reg < 4; reg++) {
            int il = wrow * 64 + rt * 16 + q * 4 + reg;
            int ig = ib0 + il;
            int ha = (int)((hp >> (8 * reg)) & 0xFFu);
            float v = 3.0e38f; int ix = 0x7fffffff;
            #pragma unroll
            for (int ct = 0; ct < 4; ct++) {
                int jl = wcol * 64 + ct * 16 + tx;
                int jg = jb0 + jl;
                float key = sqB_s[jl] - 2.0f * acc[rt][ct][reg];
                bool masked = (hostB_s[jl] == ha) || (jg == ig);
                if (!masked && (key < v || (key == v && jg < ix))) { v = key; ix = jg; }
            }
            #pragma unroll
            for (int d = 1; d < 16; d <<= 1) {
                float ov = __shfl_xor(v, d);
                int   oi = __shfl_xor(ix, d);
                if (ov < v || (ov == v && oi < ix)) { v = ov; ix = oi; }
            }
            if (tx == 0) { rowV[il * 2 + wcol] = v; rowI[il * 2 + wcol] = ix; }
        }
    }

    // cols side (off-diagonal only): for each of this lane's 4 cols, min over 16 row entries, then over q
    if (ti != tj) {
        #pragma unroll
        for (int ct = 0; ct < 4; ct++) {
            int jl = wcol * 64 + ct * 16 + tx;
            int hb = hostB_s[jl];
            float v = 3.0e38f; int ix = 0x7fffffff;
            #pragma unroll
            for (int rt = 0; rt < 4; rt++) {
                unsigned hp = hostAp[rt];
                #pragma unroll
                for (int reg = 0; reg < 4; reg++) {
                    int il = wrow * 64 + rt * 16 + q * 4 + reg;
                    int ig = ib0 + il;
                    bool masked = ((int)((hp >> (8 * reg)) & 0xFFu) == hb);
                    float key = sqA_s[il] - 2.0f * acc[rt][ct][reg];
                    if (!masked && (key < v || (key == v && ig < ix))) { v = key; ix = ig; }
                }
            }
            #pragma unroll
            for (int d = 16; d < 64; d <<= 1) {
                float ov = __shfl_xor(v, d);
                int   oi = __shfl_xor(ix, d);
                if (ov < v || (ov == v && oi < ix)) { v = ov; ix = oi; }
            }
            if (q == 0) { colV[jl * 2 + wrow] = v; colI[jl * 2 + wrow] = ix; }
        }
    }

    __syncthreads();
    if (tid < BI) {
        float v0 = rowV[tid * 2];     int x0 = rowI[tid * 2];
        float v1 = rowV[tid * 2 + 1]; int x1 = rowI[tid * 2 + 1];
        if (v1 < v0 || (v1 == v0 && x1 < x0)) { v0 = v1; x0 = x1; }
        atomicMin(&M[ib0 + tid], packKI(v0, x0));
        if (ti != tj) {
            float w0 = colV[tid * 2];     int y0 = colI[tid * 2];
            float w1 = colV[tid * 2 + 1]; int y1 = colI[tid * 2 + 1];
            if (w1 < w0 || (w1 == w0 && y1 < y0)) { w0 = w1; y0 = y1; }
            atomicMin(&M[jb0 + tid], packKI(w0, y0));
        }
    }
}

// ---------------- K5: extract index and gather e_an rows ----------------
__global__ void finalize_kernel(const unsigned long long* __restrict__ M,
                                const float* __restrict__ E, float* __restrict__ out_an) {
    int row = blockIdx.x;
    int t = threadIdx.x;   // 64
    int idx = (int)(unsigned)(M[row] & 0xFFFFFFFFull);
    float4 v = *(const float4*)&E[(size_t)idx * D + t * 4];
    *(float4*)&out_an[(size_t)row * D + t * 4] = v;
}

extern "C" void kernel_launch(void* const* d_in, const int* in_sizes, int n_in,
                              void* d_out, int out_size, void* d_ws, size_t ws_size,
                              hipStream_t stream) {
    const float* e_actv = (const float*)d_in[0];
    const float* e_ap   = (const float*)d_in[1];
    const int*   host   = (const int*)d_in[2];
    float* out = (float*)d_out;

    // workspace: M u64[N] | sq f32[N] | Ehi bf16[N*D] | Elo bf16[N*D]  (~8.3 MB)
    unsigned long long* M = (unsigned long long*)d_ws;
    float*  sq  = (float*)(M + N);
    ushort* Ehi = (ushort*)(sq + N);
    ushort* Elo = Ehi + (size_t)N * D;

    init_kernel<<<(N + 255) / 256, 256, 0, stream>>>(M);
    copy_kernel<<<2 * N * D / 4 / 256, 256, 0, stream>>>(
        (const float4*)e_actv, (const float4*)e_ap, (float4*)out);
    sqnorm_kernel<<<N, 64, 0, stream>>>(e_actv, sq);
    split_kernel<<<N * D / 4 / 256, 256, 0, stream>>>(
        (const float4*)e_actv, (ushort4*)Ehi, (ushort4*)Elo);
    dim3 grid(NT, NT);
    argmin_sym<<<grid, 256, 0, stream>>>(Ehi, Elo, host, sq, M);
    finalize_kernel<<<N, 64, 0, stream>>>(M, e_actv, out + 2 * (size_t)N * D);
}

// Round 6
// 239.942 us; speedup vs baseline: 1.0155x; 1.0155x over previous
//
#include <hip/hip_runtime.h>
#include <hip/hip_bf16.h>
#include <cstddef>

#define N 8192
#define D 256
#define BI 128
#define KT 32              // k-chunk; LDS arrays are unpadded [128][32] bf16 (64 B rows)
#define NT (N / BI)        // 64 row tiles

typedef __attribute__((ext_vector_type(8))) short short8;   // 8 bf16 = one MFMA A/B frag
typedef __attribute__((ext_vector_type(4))) float float4v;  // MFMA C/D frag

__device__ inline ushort f2bf(float x) {
    __hip_bfloat16 h = __float2bfloat16(x);
    return __builtin_bit_cast(ushort, h);
}
__device__ inline float bf2f(ushort u) {
    __hip_bfloat16 h = __builtin_bit_cast(__hip_bfloat16, u);
    return __bfloat162float(h);
}

// async 16B global -> LDS direct load (no VGPR round-trip).
// HW constraint: LDS dest is wave-uniform base + lane*16; our lds offsets are
// linear in the lane-linear index f, so the layout is exactly lane-contiguous.
__device__ inline void gl_lds16(const void* g, void* l) {
    __builtin_amdgcn_global_load_lds(
        (const __attribute__((address_space(1))) void*)g,
        (__attribute__((address_space(3))) void*)l,
        16, 0, 0);
}

// sortable pack: (monotone-uint(key) << 32) | idx  -> atomicMin == argmin with lowest-idx tie-break
__device__ inline unsigned long long packKI(float k, int idx) {
    unsigned u = __float_as_uint(k);
    u = (u & 0x80000000u) ? ~u : (u | 0x80000000u);
    return ((unsigned long long)u << 32) | (unsigned)idx;
}

// ---------------- K0: init packed-argmin array ----------------
__global__ void init_kernel(unsigned long long* __restrict__ M) {
    int i = blockIdx.x * blockDim.x + threadIdx.x;
    if (i < N) M[i] = 0xFFFFFFFFFFFFFFFFull;
}

// ---------------- K1: copy e_actv and e_ap into out[0 : 2*N*D) ----------------
__global__ void copy_kernel(const float4* __restrict__ a, const float4* __restrict__ p,
                            float4* __restrict__ out) {
    int idx = blockIdx.x * blockDim.x + threadIdx.x;
    const int total = N * D / 4;
    if (idx < total) out[idx] = a[idx];
    else             out[idx] = p[idx - total];
}

// ---------------- K2: squared row norms (fp32 exact) ----------------
__global__ void sqnorm_kernel(const float* __restrict__ e, float* __restrict__ sq) {
    int row = blockIdx.x;
    int t = threadIdx.x;   // 64
    const float4* r4 = (const float4*)(e + (size_t)row * D);
    float4 v = r4[t];
    float s = v.x * v.x + v.y * v.y + v.z * v.z + v.w * v.w;
    #pragma unroll
    for (int off = 32; off; off >>= 1) s += __shfl_down(s, off);
    if (t == 0) sq[row] = s;
}

// ---------------- K3: split fp32 -> bf16 hi + bf16 lo ----------------
__global__ void split_kernel(const float4* __restrict__ E,
                             ushort4* __restrict__ hi, ushort4* __restrict__ lo) {
    int idx = blockIdx.x * blockDim.x + threadIdx.x;   // over N*D/4
    float4 v = E[idx];
    ushort4 h, l;
    h.x = f2bf(v.x); l.x = f2bf(v.x - bf2f(h.x));
    h.y = f2bf(v.y); l.y = f2bf(v.y - bf2f(h.y));
    h.z = f2bf(v.z); l.z = f2bf(v.z - bf2f(h.z));
    h.w = f2bf(v.w); l.w = f2bf(v.w - bf2f(h.w));
    hi[idx] = h; lo[idx] = l;
}

// ---------------- K4: symmetric split-bf16 MFMA + dual-sided masked argmin ----------------
// Upper-triangle tiles only (ti <= tj): each 128x128 tile of dot(i,j) updates
//   rows side: argmin_i over j with key = sq[j] - 2*dot
//   cols side: argmin_j over i with key = sq[i] - 2*dot   (skipped on diagonal)
// Partials merged globally via atomicMin on packed (key,idx).
__launch_bounds__(256)
__global__ void argmin_sym(const ushort* __restrict__ Ehi, const ushort* __restrict__ Elo,
                           const int* __restrict__ host, const float* __restrict__ sq,
                           unsigned long long* __restrict__ M) {
    const int ti = blockIdx.y;
    const int tj = blockIdx.x;
    if (tj < ti) return;                        // lower triangle: exit immediately

    __shared__ __align__(16) ushort lds[4 * BI * KT];   // 32768 B, unpadded lane-linear
    __shared__ float sqA_s[BI], sqB_s[BI];
    __shared__ int   hostB_s[BI];
    ushort* Ahi_s = lds;
    ushort* Alo_s = lds + 1 * BI * KT;
    ushort* Bhi_s = lds + 2 * BI * KT;
    ushort* Blo_s = lds + 3 * BI * KT;

    const int ib0 = ti * BI;
    const int jb0 = tj * BI;
    const int tid = threadIdx.x;
    const int lane = tid & 63;
    const int wave = tid >> 6;      // 0..3
    const int wrow = wave >> 1;     // 0..1
    const int wcol = wave & 1;      // 0..1
    const int tx = lane & 15;       // 0..15
    const int q  = lane >> 4;       // 0..3

    // hostA packed per rt: 4 bytes = hosts of rows (rt,reg) for this lane (host < 64)
    unsigned hostAp[4];
    #pragma unroll
    for (int rt = 0; rt < 4; rt++) {
        unsigned p = 0;
        #pragma unroll
        for (int reg = 0; reg < 4; reg++) {
            int hv = host[ib0 + wrow * 64 + rt * 16 + q * 4 + reg];
            p |= ((unsigned)hv & 0xFFu) << (8 * reg);
        }
        hostAp[rt] = p;
    }

    float4v acc[4][4];   // [rt][ct]
    #pragma unroll
    for (int rt = 0; rt < 4; rt++)
        #pragma unroll
        for (int ct = 0; ct < 4; ct++) acc[rt][ct] = (float4v)(0.0f);

    for (int kt = 0; kt < D; kt += KT) {
        __syncthreads();   // previous readers done; also drains prior async loads
        // stage 4 arrays of 128 rows x 32 bf16 (8 KB each) via direct global->LDS.
        // f = tid + t*256 in 0..511; row = f>>2, c = f&3; lds byte off = f*16
        // (row*64B + c*16B == f*16B -> lane-contiguous, HW-valid).
        #pragma unroll
        for (int t = 0; t < 2; t++) {
            int f = tid + t * 256;
            int row = f >> 2;
            int c = f & 3;
            size_t gA = (size_t)(ib0 + row) * D + kt + c * 8;
            size_t gB = (size_t)(jb0 + row) * D + kt + c * 8;
            int o = f * 8;   // ushort offset: 16 B per f
            gl_lds16(&Ehi[gA], &Ahi_s[o]);
            gl_lds16(&Elo[gA], &Alo_s[o]);
            gl_lds16(&Ehi[gB], &Bhi_s[o]);
            gl_lds16(&Elo[gB], &Blo_s[o]);
        }
        if (kt == 0 && tid < BI) {
            sqA_s[tid] = sq[ib0 + tid];
            sqB_s[tid] = sq[jb0 + tid];
            hostB_s[tid] = host[jb0 + tid];
        }
        __syncthreads();   // vmcnt(0)+barrier: async loads complete for whole block

        short8 ah[4], al[4], bh[4], bl[4];
        #pragma unroll
        for (int rt = 0; rt < 4; rt++) {
            int o = (wrow * 64 + rt * 16 + tx) * KT + q * 8;
            ah[rt] = *(const short8*)&Ahi_s[o];
            al[rt] = *(const short8*)&Alo_s[o];
        }
        #pragma unroll
        for (int ct = 0; ct < 4; ct++) {
            int o = (wcol * 64 + ct * 16 + tx) * KT + q * 8;
            bh[ct] = *(const short8*)&Bhi_s[o];
            bl[ct] = *(const short8*)&Blo_s[o];
        }
        #pragma unroll
        for (int rt = 0; rt < 4; rt++)
            #pragma unroll
            for (int ct = 0; ct < 4; ct++) {
                acc[rt][ct] = __builtin_amdgcn_mfma_f32_16x16x32_bf16(ah[rt], bh[ct], acc[rt][ct], 0, 0, 0);
                acc[rt][ct] = __builtin_amdgcn_mfma_f32_16x16x32_bf16(ah[rt], bl[ct], acc[rt][ct], 0, 0, 0);
                acc[rt][ct] = __builtin_amdgcn_mfma_f32_16x16x32_bf16(al[rt], bh[ct], acc[rt][ct], 0, 0, 0);
            }
    }

    // ---- epilogue: dual-sided argmin. Reuse lds head as reduction scratch. ----
    __syncthreads();                       // all frag reads done before scratch overwrite
    float* rowV = (float*)lds;             // [128][2] (by wcol)
    int*   rowI = (int*)lds + 256;
    float* colV = (float*)lds + 512;       // [128][2] (by wrow)
    int*   colI = (int*)lds + 768;

    // rows side: for each of this lane's 16 rows, min over its 4 ct entries, then over tx
    #pragma unroll
    for (int rt = 0; rt < 4; rt++) {
        unsigned hp = hostAp[rt];
        #pragma unroll
        for (int reg = 0; reg < 4; reg++) {
            int il = wrow * 64 + rt * 16 + q * 4 + reg;
            int ig = ib0 + il;
            int ha = (int)((hp >> (8 * reg)) & 0xFFu);
            float v = 3.0e38f; int ix = 0x7fffffff;
            #pragma unroll
            for (int ct = 0; ct < 4; ct++) {
                int jl = wcol * 64 + ct * 16 + tx;
                int jg = jb0 + jl;
                float key = sqB_s[jl] - 2.0f * acc[rt][ct][reg];
                bool masked = (hostB_s[jl] == ha) || (jg == ig);
                if (!masked && (key < v || (key == v && jg < ix))) { v = key; ix = jg; }
            }
            #pragma unroll
            for (int d = 1; d < 16; d <<= 1) {
                float ov = __shfl_xor(v, d);
                int   oi = __shfl_xor(ix, d);
                if (ov < v || (ov == v && oi < ix)) { v = ov; ix = oi; }
            }
            if (tx == 0) { rowV[il * 2 + wcol] = v; rowI[il * 2 + wcol] = ix; }
        }
    }

    // cols side (off-diagonal only): for each of this lane's 4 cols, min over 16 row entries, then over q
    if (ti != tj) {
        #pragma unroll
        for (int ct = 0; ct < 4; ct++) {
            int jl = wcol * 64 + ct * 16 + tx;
            int hb = hostB_s[jl];
            float v = 3.0e38f; int ix = 0x7fffffff;
            #pragma unroll
            for (int rt = 0; rt < 4; rt++) {
                unsigned hp = hostAp[rt];
                #pragma unroll
                for (int reg = 0; reg < 4; reg++) {
                    int il = wrow * 64 + rt * 16 + q * 4 + reg;
                    int ig = ib0 + il;
                    bool masked = ((int)((hp >> (8 * reg)) & 0xFFu) == hb);
                    float key = sqA_s[il] - 2.0f * acc[rt][ct][reg];
                    if (!masked && (key < v || (key == v && ig < ix))) { v = key; ix = ig; }
                }
            }
            #pragma unroll
            for (int d = 16; d < 64; d <<= 1) {
                float ov = __shfl_xor(v, d);
                int   oi = __shfl_xor(ix, d);
                if (ov < v || (ov == v && oi < ix)) { v = ov; ix = oi; }
            }
            if (q == 0) { colV[jl * 2 + wrow] = v; colI[jl * 2 + wrow] = ix; }
        }
    }

    __syncthreads();
    if (tid < BI) {
        float v0 = rowV[tid * 2];     int x0 = rowI[tid * 2];
        float v1 = rowV[tid * 2 + 1]; int x1 = rowI[tid * 2 + 1];
        if (v1 < v0 || (v1 == v0 && x1 < x0)) { v0 = v1; x0 = x1; }
        atomicMin(&M[ib0 + tid], packKI(v0, x0));
        if (ti != tj) {
            float w0 = colV[tid * 2];     int y0 = colI[tid * 2];
            float w1 = colV[tid * 2 + 1]; int y1 = colI[tid * 2 + 1];
            if (w1 < w0 || (w1 == w0 && y1 < y0)) { w0 = w1; y0 = y1; }
            atomicMin(&M[jb0 + tid], packKI(w0, y0));
        }
    }
}

// ---------------- K5: extract index and gather e_an rows ----------------
__global__ void finalize_kernel(const unsigned long long* __restrict__ M,
                                const float* __restrict__ E, float* __restrict__ out_an) {
    int row = blockIdx.x;
    int t = threadIdx.x;   // 64
    int idx = (int)(unsigned)(M[row] & 0xFFFFFFFFull);
    float4 v = *(const float4*)&E[(size_t)idx * D + t * 4];
    *(float4*)&out_an[(size_t)row * D + t * 4] = v;
}

extern "C" void kernel_launch(void* const* d_in, const int* in_sizes, int n_in,
                              void* d_out, int out_size, void* d_ws, size_t ws_size,
                              hipStream_t stream) {
    const float* e_actv = (const float*)d_in[0];
    const float* e_ap   = (const float*)d_in[1];
    const int*   host   = (const int*)d_in[2];
    float* out = (float*)d_out;

    // workspace: M u64[N] | sq f32[N] | Ehi bf16[N*D] | Elo bf16[N*D]  (~8.3 MB)
    unsigned long long* M = (unsigned long long*)d_ws;
    float*  sq  = (float*)(M + N);
    ushort* Ehi = (ushort*)(sq + N);
    ushort* Elo = Ehi + (size_t)N * D;

    init_kernel<<<(N + 255) / 256, 256, 0, stream>>>(M);
    copy_kernel<<<2 * N * D / 4 / 256, 256, 0, stream>>>(
        (const float4*)e_actv, (const float4*)e_ap, (float4*)out);
    sqnorm_kernel<<<N, 64, 0, stream>>>(e_actv, sq);
    split_kernel<<<N * D / 4 / 256, 256, 0, stream>>>(
        (const float4*)e_actv, (ushort4*)Ehi, (ushort4*)Elo);
    dim3 grid(NT, NT);
    argmin_sym<<<grid, 256, 0, stream>>>(Ehi, Elo, host, sq, M);
    finalize_kernel<<<N, 64, 0, stream>>>(M, e_actv, out + 2 * (size_t)N * D);
}

// Round 7
// 203.359 us; speedup vs baseline: 1.1982x; 1.1799x over previous
//
#include <hip/hip_runtime.h>
#include <hip/hip_bf16.h>
#include <cmath>
#include <cstddef>

#define N 8192
#define D 256
#define BI 128
#define KT 32              // k-chunk; LDS arrays are unpadded [128][32] bf16 (64 B rows)
#define NT (N / BI)        // 64 row tiles
#define NTRI (NT * (NT + 1) / 2)   // 2080 upper-triangle tiles

typedef __attribute__((ext_vector_type(8))) short short8;   // 8 bf16 = one MFMA A/B frag
typedef __attribute__((ext_vector_type(4))) float float4v;  // MFMA C/D frag

__device__ inline ushort f2bf(float x) {
    __hip_bfloat16 h = __float2bfloat16(x);
    return __builtin_bit_cast(ushort, h);
}
__device__ inline float bf2f(ushort u) {
    __hip_bfloat16 h = __builtin_bit_cast(__hip_bfloat16, u);
    return __bfloat162float(h);
}

// async 16B global -> LDS direct load (no VGPR round-trip); lane-contiguous dest.
__device__ inline void gl_lds16(const void* g, void* l) {
    __builtin_amdgcn_global_load_lds(
        (const __attribute__((address_space(1))) void*)g,
        (__attribute__((address_space(3))) void*)l,
        16, 0, 0);
}

// sortable pack: (monotone-uint(key) << 32) | idx  -> atomicMin == argmin, lowest-idx tie-break
__device__ inline unsigned long long packKI(float k, int idx) {
    unsigned u = __float_as_uint(k);
    u = (u & 0x80000000u) ? ~u : (u | 0x80000000u);
    return ((unsigned long long)u << 32) | (unsigned)idx;
}

// T(t) = pairs before row t in row-major upper triangle (incl. diagonal), NT=64
__device__ inline int triT(int t) { return t * (129 - t) / 2; }

// ---------------- K1: fused prep — M init, copy both inputs to out, sqnorm, bf16 hi/lo split ----
// grid 1024 x 256; wave-aligned so each wave iteration covers exactly one row for sqnorm.
__global__ void prep_kernel(const float4* __restrict__ a, const float4* __restrict__ p,
                            float4* __restrict__ out, float* __restrict__ sq,
                            ushort4* __restrict__ hi, ushort4* __restrict__ lo,
                            unsigned long long* __restrict__ M) {
    const int gsz = gridDim.x * blockDim.x;          // 262144, multiple of 64
    const int g0 = blockIdx.x * blockDim.x + threadIdx.x;
    const int total = N * D / 4;                     // 524288 float4

    // e_actv: copy + split + per-row sqnorm (one row per wave per iter: 64 float4 = 1 row)
    for (int idx = g0; idx < total; idx += gsz) {
        float4 v = a[idx];
        out[idx] = v;
        ushort4 h, l;
        h.x = f2bf(v.x); l.x = f2bf(v.x - bf2f(h.x));
        h.y = f2bf(v.y); l.y = f2bf(v.y - bf2f(h.y));
        h.z = f2bf(v.z); l.z = f2bf(v.z - bf2f(h.z));
        h.w = f2bf(v.w); l.w = f2bf(v.w - bf2f(h.w));
        hi[idx] = h; lo[idx] = l;
        float s = v.x * v.x + v.y * v.y + v.z * v.z + v.w * v.w;
        #pragma unroll
        for (int off = 32; off; off >>= 1) s += __shfl_down(s, off);
        if ((threadIdx.x & 63) == 0) sq[idx >> 6] = s;
    }
    // e_ap: plain copy into second output slot
    for (int idx = g0; idx < total; idx += gsz) out[total + idx] = p[idx];
    // M init
    for (int i = g0; i < N; i += gsz) M[i] = 0xFFFFFFFFFFFFFFFFull;
}

// ---------------- K2: symmetric split-bf16 MFMA + dual-sided masked argmin ----------------
// Balanced 1D grid over the 2080 upper-triangle tiles (no dead blocks, no CU imbalance).
__launch_bounds__(256)
__global__ void argmin_sym(const ushort* __restrict__ Ehi, const ushort* __restrict__ Elo,
                           const int* __restrict__ host, const float* __restrict__ sq,
                           unsigned long long* __restrict__ M) {
    // decode linear tile id -> (ti, tj), ti <= tj
    const int b = blockIdx.x;
    int ti = (int)floor(64.5 - sqrt(64.5 * 64.5 - 2.0 * (double)b));
    while (triT(ti + 1) <= b) ti++;
    while (triT(ti) > b) ti--;
    const int tj = ti + (b - triT(ti));

    __shared__ __align__(16) ushort lds[4 * BI * KT];   // 32768 B, unpadded lane-linear
    __shared__ float sqA_s[BI], sqB_s[BI];
    __shared__ int   hostB_s[BI];
    ushort* Ahi_s = lds;
    ushort* Alo_s = lds + 1 * BI * KT;
    ushort* Bhi_s = lds + 2 * BI * KT;
    ushort* Blo_s = lds + 3 * BI * KT;

    const int ib0 = ti * BI;
    const int jb0 = tj * BI;
    const int tid = threadIdx.x;
    const int lane = tid & 63;
    const int wave = tid >> 6;      // 0..3
    const int wrow = wave >> 1;     // 0..1
    const int wcol = wave & 1;      // 0..1
    const int tx = lane & 15;       // 0..15
    const int q  = lane >> 4;       // 0..3

    // hostA packed per rt: 4 bytes = hosts of rows (rt,reg) for this lane (host < 64)
    unsigned hostAp[4];
    #pragma unroll
    for (int rt = 0; rt < 4; rt++) {
        unsigned p = 0;
        #pragma unroll
        for (int reg = 0; reg < 4; reg++) {
            int hv = host[ib0 + wrow * 64 + rt * 16 + q * 4 + reg];
            p |= ((unsigned)hv & 0xFFu) << (8 * reg);
        }
        hostAp[rt] = p;
    }

    float4v acc[4][4];   // [rt][ct]
    #pragma unroll
    for (int rt = 0; rt < 4; rt++)
        #pragma unroll
        for (int ct = 0; ct < 4; ct++) acc[rt][ct] = (float4v)(0.0f);

    for (int kt = 0; kt < D; kt += KT) {
        __syncthreads();   // previous readers done; also drains prior async loads
        // stage 4 arrays of 128x32 bf16 (8 KB each) via direct global->LDS (lane-linear)
        #pragma unroll
        for (int t = 0; t < 2; t++) {
            int f = tid + t * 256;
            int row = f >> 2;
            int c = f & 3;
            size_t gA = (size_t)(ib0 + row) * D + kt + c * 8;
            size_t gB = (size_t)(jb0 + row) * D + kt + c * 8;
            int o = f * 8;   // ushort offset: 16 B per f
            gl_lds16(&Ehi[gA], &Ahi_s[o]);
            gl_lds16(&Elo[gA], &Alo_s[o]);
            gl_lds16(&Ehi[gB], &Bhi_s[o]);
            gl_lds16(&Elo[gB], &Blo_s[o]);
        }
        if (kt == 0 && tid < BI) {
            sqA_s[tid] = sq[ib0 + tid];
            sqB_s[tid] = sq[jb0 + tid];
            hostB_s[tid] = host[jb0 + tid];
        }
        __syncthreads();   // vmcnt(0)+barrier: async loads complete for whole block

        short8 ah[4], al[4], bh[4], bl[4];
        #pragma unroll
        for (int rt = 0; rt < 4; rt++) {
            int o = (wrow * 64 + rt * 16 + tx) * KT + q * 8;
            ah[rt] = *(const short8*)&Ahi_s[o];
            al[rt] = *(const short8*)&Alo_s[o];
        }
        #pragma unroll
        for (int ct = 0; ct < 4; ct++) {
            int o = (wcol * 64 + ct * 16 + tx) * KT + q * 8;
            bh[ct] = *(const short8*)&Bhi_s[o];
            bl[ct] = *(const short8*)&Blo_s[o];
        }
        // pass-outer order: 16 independent MFMAs between dependent ones on the
        // same acc; per-acc accumulation order (hh,hl,lh) unchanged -> bit-exact.
        #pragma unroll
        for (int rt = 0; rt < 4; rt++)
            #pragma unroll
            for (int ct = 0; ct < 4; ct++)
                acc[rt][ct] = __builtin_amdgcn_mfma_f32_16x16x32_bf16(ah[rt], bh[ct], acc[rt][ct], 0, 0, 0);
        #pragma unroll
        for (int rt = 0; rt < 4; rt++)
            #pragma unroll
            for (int ct = 0; ct < 4; ct++)
                acc[rt][ct] = __builtin_amdgcn_mfma_f32_16x16x32_bf16(ah[rt], bl[ct], acc[rt][ct], 0, 0, 0);
        #pragma unroll
        for (int rt = 0; rt < 4; rt++)
            #pragma unroll
            for (int ct = 0; ct < 4; ct++)
                acc[rt][ct] = __builtin_amdgcn_mfma_f32_16x16x32_bf16(al[rt], bh[ct], acc[rt][ct], 0, 0, 0);
    }

    // ---- epilogue: dual-sided argmin. Reuse lds head as reduction scratch. ----
    __syncthreads();                       // all frag reads done before scratch overwrite
    float* rowV = (float*)lds;             // [128][2] (by wcol)
    int*   rowI = (int*)lds + 256;
    float* colV = (float*)lds + 512;       // [128][2] (by wrow)
    int*   colI = (int*)lds + 768;

    // rows side: for each of this lane's 16 rows, min over its 4 ct entries, then over tx
    #pragma unroll
    for (int rt = 0; rt < 4; rt++) {
        unsigned hp = hostAp[rt];
        #pragma unroll
        for (int reg = 0; reg < 4; reg++) {
            int il = wrow * 64 + rt * 16 + q * 4 + reg;
            int ig = ib0 + il;
            int ha = (int)((hp >> (8 * reg)) & 0xFFu);
            float v = 3.0e38f; int ix = 0x7fffffff;
            #pragma unroll
            for (int ct = 0; ct < 4; ct++) {
                int jl = wcol * 64 + ct * 16 + tx;
                int jg = jb0 + jl;
                float key = sqB_s[jl] - 2.0f * acc[rt][ct][reg];
                bool masked = (hostB_s[jl] == ha) || (jg == ig);
                if (!masked && (key < v || (key == v && jg < ix))) { v = key; ix = jg; }
            }
            #pragma unroll
            for (int d = 1; d < 16; d <<= 1) {
                float ov = __shfl_xor(v, d);
                int   oi = __shfl_xor(ix, d);
                if (ov < v || (ov == v && oi < ix)) { v = ov; ix = oi; }
            }
            if (tx == 0) { rowV[il * 2 + wcol] = v; rowI[il * 2 + wcol] = ix; }
        }
    }

    // cols side (off-diagonal only): per lane's 4 cols, min over 16 row entries, then over q
    if (ti != tj) {
        #pragma unroll
        for (int ct = 0; ct < 4; ct++) {
            int jl = wcol * 64 + ct * 16 + tx;
            int hb = hostB_s[jl];
            float v = 3.0e38f; int ix = 0x7fffffff;
            #pragma unroll
            for (int rt = 0; rt < 4; rt++) {
                unsigned hp = hostAp[rt];
                #pragma unroll
                for (int reg = 0; reg < 4; reg++) {
                    int il = wrow * 64 + rt * 16 + q * 4 + reg;
                    int ig = ib0 + il;
                    bool masked = ((int)((hp >> (8 * reg)) & 0xFFu) == hb);
                    float key = sqA_s[il] - 2.0f * acc[rt][ct][reg];
                    if (!masked && (key < v || (key == v && ig < ix))) { v = key; ix = ig; }
                }
            }
            #pragma unroll
            for (int d = 16; d < 64; d <<= 1) {
                float ov = __shfl_xor(v, d);
                int   oi = __shfl_xor(ix, d);
                if (ov < v || (ov == v && oi < ix)) { v = ov; ix = oi; }
            }
            if (q == 0) { colV[jl * 2 + wrow] = v; colI[jl * 2 + wrow] = ix; }
        }
    }

    __syncthreads();
    if (tid < BI) {
        float v0 = rowV[tid * 2];     int x0 = rowI[tid * 2];
        float v1 = rowV[tid * 2 + 1]; int x1 = rowI[tid * 2 + 1];
        if (v1 < v0 || (v1 == v0 && x1 < x0)) { v0 = v1; x0 = x1; }
        atomicMin(&M[ib0 + tid], packKI(v0, x0));
        if (ti != tj) {
            float w0 = colV[tid * 2];     int y0 = colI[tid * 2];
            float w1 = colV[tid * 2 + 1]; int y1 = colI[tid * 2 + 1];
            if (w1 < w0 || (w1 == w0 && y1 < y0)) { w0 = w1; y0 = y1; }
            atomicMin(&M[jb0 + tid], packKI(w0, y0));
        }
    }
}

// ---------------- K3: extract index and gather e_an rows ----------------
__global__ void finalize_kernel(const unsigned long long* __restrict__ M,
                                const float* __restrict__ E, float* __restrict__ out_an) {
    int row = blockIdx.x;
    int t = threadIdx.x;   // 64
    int idx = (int)(unsigned)(M[row] & 0xFFFFFFFFull);
    float4 v = *(const float4*)&E[(size_t)idx * D + t * 4];
    *(float4*)&out_an[(size_t)row * D + t * 4] = v;
}

extern "C" void kernel_launch(void* const* d_in, const int* in_sizes, int n_in,
                              void* d_out, int out_size, void* d_ws, size_t ws_size,
                              hipStream_t stream) {
    const float* e_actv = (const float*)d_in[0];
    const float* e_ap   = (const float*)d_in[1];
    const int*   host   = (const int*)d_in[2];
    float* out = (float*)d_out;

    // workspace: M u64[N] | sq f32[N] | Ehi bf16[N*D] | Elo bf16[N*D]  (~8.3 MB)
    unsigned long long* M = (unsigned long long*)d_ws;
    float*  sq  = (float*)(M + N);
    ushort* Ehi = (ushort*)(sq + N);
    ushort* Elo = Ehi + (size_t)N * D;

    prep_kernel<<<1024, 256, 0, stream>>>(
        (const float4*)e_actv, (const float4*)e_ap, (float4*)out,
        sq, (ushort4*)Ehi, (ushort4*)Elo, M);
    argmin_sym<<<NTRI, 256, 0, stream>>>(Ehi, Elo, host, sq, M);
    finalize_kernel<<<N, 64, 0, stream>>>(M, e_actv, out + 2 * (size_t)N * D);
}